// Round 1
// baseline (382.534 us; speedup 1.0000x reference)
//
#include <hip/hip_runtime.h>

// RelMultiHeadSelfAttention (Transformer-XL) on gfx950.
// B=2, T=1024, M=1024, L=J=2048, D=1024, H=16, dh=64. fp32 in/out, bf16 MFMA inside.
//
// Pipeline: prep(convert) -> gemm_qr -> gemm_kv -> attn -> gemm_out.
// Rel-shift: with p = j+1023-i: p<=2047 -> qv[i].r[p]; p==2048 -> 0; p>=2049 -> qv[i+1].r[p-2049].
// SCALE*log2(e) folded into qu/qv so softmax runs in exp2 domain.
// Workspace use: ~54 MB.

typedef unsigned short u16;
typedef unsigned int u32;
typedef short bf16x8 __attribute__((ext_vector_type(8)));
typedef float f32x4 __attribute__((ext_vector_type(4)));

#define MFMA16(a, b, c) __builtin_amdgcn_mfma_f32_16x16x32_bf16(a, b, c, 0, 0, 0)

__device__ __forceinline__ u16 f2bf(float f) {  // RNE fp32 -> bf16
  u32 u = __float_as_uint(f);
  u32 r = (u + 0x7fffu + ((u >> 16) & 1u)) >> 16;
  return (u16)r;
}

__device__ __forceinline__ void async16(void* lds, const void* g) {
  __builtin_amdgcn_global_load_lds(
      (const __attribute__((address_space(1))) u32*)g,
      (__attribute__((address_space(3))) u32*)lds, 16, 0, 0);
}

// ---------------- prep: fp32 -> bf16 conversions -----------------------------
__global__ void prep_kernel(const float* __restrict__ x, const float* __restrict__ mem,
                            const float* __restrict__ pos,
                            const float* __restrict__ qw, const float* __restrict__ kw,
                            const float* __restrict__ vw, const float* __restrict__ rw,
                            const float* __restrict__ ow,
                            u16* __restrict__ catb, u16* __restrict__ posb,
                            u16* __restrict__ wqb, u16* __restrict__ wkb,
                            u16* __restrict__ wvb, u16* __restrict__ wrb,
                            u16* __restrict__ wob) {
  const int seg = blockIdx.y;
  const int vid = blockIdx.x * blockDim.x + threadIdx.x;
  const float* src = nullptr;
  u16* dst = nullptr;
  int count = 0;
  switch (seg) {
    case 0: count = (2 * 2048 * 1024) / 4; dst = catb; break;
    case 1: count = (2048 * 1024) / 4; src = pos; dst = posb; break;
    case 2: count = (1024 * 1024) / 4; src = qw; dst = wqb; break;
    case 3: count = (1024 * 1024) / 4; src = kw; dst = wkb; break;
    case 4: count = (1024 * 1024) / 4; src = vw; dst = wvb; break;
    case 5: count = (1024 * 1024) / 4; src = rw; dst = wrb; break;
    case 6: count = (1024 * 1024) / 4; src = ow; dst = wob; break;
  }
  if (vid >= count) return;
  float4 f;
  if (seg == 0) {
    int e = vid * 4;                 // element index into cat [2][2048][1024]
    int col = e & 1023;
    int row = (e >> 10) & 2047;      // time position within cat
    int b = e >> 21;
    const float* s2 = (row < 1024)
                          ? (mem + ((size_t)(b * 1024 + row) * 1024 + col))
                          : (x + ((size_t)(b * 1024 + (row - 1024)) * 1024 + col));
    f = *(const float4*)s2;
  } else {
    f = *(const float4*)(src + (size_t)vid * 4);
  }
  ushort4 o4;
  o4.x = f2bf(f.x); o4.y = f2bf(f.y); o4.z = f2bf(f.z); o4.w = f2bf(f.w);
  *(ushort4*)(dst + (size_t)vid * 4) = o4;
}

// ---------------- GEMM core: C[128x128] = A[128xK] * W[128xK]^T, K=1024 ------
// m97-style: global_load_lds width 16, BK=32, XOR chunk swizzle f(row)=(row>>1)&3.
__device__ __forceinline__ void gemm_core(const u16* __restrict__ A, const u16* __restrict__ W,
                                          u16* As, u16* Bs, int m0, int n0, bool qmap,
                                          f32x4 acc[4][4]) {
  const int t = threadIdx.x;
  const int lane = t & 63, wid = t >> 6;
  const int colL = lane & 15, rg = lane >> 4;
  const int wm = (wid >> 1) * 64, wn = (wid & 1) * 64;
  for (int kt = 0; kt < 32; ++kt) {
    __syncthreads();
#pragma unroll
    for (int pass = 0; pass < 2; ++pass) {
      int slot = t + pass * 256;      // 0..511 -> 128 rows x 4 16B-chunks
      int row = slot >> 2, ch = slot & 3;
      int sch = ch ^ ((row >> 1) & 3);
      int ar = m0 + row;
      if (qmap) ar = ((ar >> 10) << 11) + 1024 + (ar & 1023);  // q rows live inside cat
      async16(As + slot * 8, A + (size_t)ar * 1024 + kt * 32 + sch * 8);
      async16(Bs + slot * 8, W + (size_t)(n0 + row) * 1024 + kt * 32 + sch * 8);
    }
    __syncthreads();
    bf16x8 af[4], bfr[4];
#pragma unroll
    for (int mi = 0; mi < 4; ++mi) {
      int r = wm + mi * 16 + colL;
      af[mi] = *(const bf16x8*)(As + r * 32 + (rg ^ ((r >> 1) & 3)) * 8);
    }
#pragma unroll
    for (int ni = 0; ni < 4; ++ni) {
      int r = wn + ni * 16 + colL;
      bfr[ni] = *(const bf16x8*)(Bs + r * 32 + (rg ^ ((r >> 1) & 3)) * 8);
    }
#pragma unroll
    for (int mi = 0; mi < 4; ++mi)
#pragma unroll
      for (int ni = 0; ni < 4; ++ni)
        acc[mi][ni] = MFMA16(af[mi], bfr[ni], acc[mi][ni]);
  }
}

// ---------------- q+r projections ----------------
// blocks [0,128): q from cat-rows (row-mapped), epilogue -> qu/qv with bias+scale
// blocks [128,256): r from pos_emb, epilogue -> r_b [H][2048][64]
__global__ __launch_bounds__(256, 2) void gemm_qr(
    const u16* __restrict__ catb, const u16* __restrict__ posb,
    const u16* __restrict__ wqb, const u16* __restrict__ wrb,
    const float* __restrict__ bu, const float* __restrict__ bv,
    u16* __restrict__ qub, u16* __restrict__ qvb, u16* __restrict__ rbuf) {
  __shared__ u16 As[128 * 32], Bs[128 * 32];
  const int bid = blockIdx.x;
  const bool isq = bid < 128;
  const int rem = bid & 127;
  const int mt = rem >> 3, nt = rem & 7;
  const int m0 = mt * 128, n0 = nt * 128;
  f32x4 acc[4][4];
  f32x4 zz = {0.f, 0.f, 0.f, 0.f};
#pragma unroll
  for (int a1 = 0; a1 < 4; ++a1)
#pragma unroll
    for (int a2 = 0; a2 < 4; ++a2) acc[a1][a2] = zz;
  gemm_core(isq ? catb : posb, isq ? wqb : wrb, As, Bs, m0, n0, isq, acc);
  const int t = threadIdx.x, lane = t & 63, wid = t >> 6;
  const int colL = lane & 15, rg = lane >> 4;
  const int wm = (wid >> 1) * 64, wn = (wid & 1) * 64;
  const float sc = 0.18033688f;  // 0.125 * log2(e)
#pragma unroll
  for (int mi = 0; mi < 4; ++mi)
#pragma unroll
    for (int ni = 0; ni < 4; ++ni)
#pragma unroll
      for (int e = 0; e < 4; ++e) {
        int m = m0 + wm + mi * 16 + rg * 4 + e;
        int n = n0 + wn + ni * 16 + colL;
        float val = acc[mi][ni][e];
        int hh = n >> 6, dd = n & 63;
        if (isq) {
          int bb = m >> 10, tq = m & 1023;
          size_t ad = (((size_t)(bb * 16 + hh)) * 1024 + tq) * 64 + dd;
          qub[ad] = f2bf((val + bu[n]) * sc);
          qvb[ad] = f2bf((val + bv[n]) * sc);
        } else {
          rbuf[((size_t)hh * 2048 + m) * 64 + dd] = f2bf(val);
        }
      }
}

// ---------------- k+v projections ----------------
// blocks [0,256): k -> [B][H][2048][64]; blocks [256,512): v -> transposed [B][H][64][2048]
__global__ __launch_bounds__(256, 2) void gemm_kv(
    const u16* __restrict__ catb, const u16* __restrict__ wkb, const u16* __restrict__ wvb,
    u16* __restrict__ kbuf, u16* __restrict__ vtbuf) {
  __shared__ u16 As[128 * 32], Bs[128 * 32];
  const int bid = blockIdx.x;
  const bool isk = bid < 256;
  const int rem = bid & 255;
  const int mt = rem >> 3, nt = rem & 7;
  const int m0 = mt * 128, n0 = nt * 128;
  f32x4 acc[4][4];
  f32x4 zz = {0.f, 0.f, 0.f, 0.f};
#pragma unroll
  for (int a1 = 0; a1 < 4; ++a1)
#pragma unroll
    for (int a2 = 0; a2 < 4; ++a2) acc[a1][a2] = zz;
  gemm_core(catb, isk ? wkb : wvb, As, Bs, m0, n0, false, acc);
  const int t = threadIdx.x, lane = t & 63, wid = t >> 6;
  const int colL = lane & 15, rg = lane >> 4;
  const int wm = (wid >> 1) * 64, wn = (wid & 1) * 64;
#pragma unroll
  for (int mi = 0; mi < 4; ++mi)
#pragma unroll
    for (int ni = 0; ni < 4; ++ni)
#pragma unroll
      for (int e = 0; e < 4; ++e) {
        int m = m0 + wm + mi * 16 + rg * 4 + e;
        int n = n0 + wn + ni * 16 + colL;
        float val = acc[mi][ni][e];
        int bb = m >> 11, j = m & 2047;
        int hh = n >> 6, dd = n & 63;
        if (isk)
          kbuf[(((size_t)(bb * 16 + hh)) * 2048 + j) * 64 + dd] = f2bf(val);
        else
          vtbuf[(((size_t)(bb * 16 + hh)) * 64 + dd) * 2048 + j] = f2bf(val);
      }
}

// ---------------- fused rel-pos flash attention ----------------
// 512 blocks x 256 thr; wave-autonomous: wave = 16 q-rows of one (b,h); 32 key-tiles of 64.
__global__ __launch_bounds__(256, 2) void attn_kernel(
    const u16* __restrict__ qu, const u16* __restrict__ qv, const u16* __restrict__ kmat,
    const u16* __restrict__ vtm, const u16* __restrict__ rmat, u16* __restrict__ aout) {
  __shared__ float Ulds[4][16 * 84 + 4];  // per-wave U scratch (stride 84 breaks bank aliasing)
  __shared__ u16 Plds[4][1024];           // per-wave P scratch (chunk-XOR swizzled)
  const int t = threadIdx.x;
  const int wid = t >> 6, lane = t & 63;
  const int colL = lane & 15, rg = lane >> 4;
  const int bid = blockIdx.x;
  const int bh = bid >> 4;            // 0..31
  const int b = bh >> 4, h = bh & 15;
  const int i0 = (bid & 15) * 64 + wid * 16;  // wave's q-row base

  const u16* qub = qu + (size_t)bh * (1024 * 64);
  const u16* qvb = qv + (size_t)bh * (1024 * 64);
  const u16* kb = kmat + (size_t)bh * (2048 * 64);
  const u16* vb = vtm + (size_t)bh * (64 * 2048);
  const u16* rb = rmat + (size_t)h * (2048 * 64);

  bf16x8 aqu[2], aqv[2], aqs[2];
  {
    int r0 = i0 + colL;
    int rs = (r0 + 1 < 1024) ? r0 + 1 : 1023;  // row+1 for leak; clamp (unused at i=1023)
#pragma unroll
    for (int kx = 0; kx < 2; ++kx) {
      aqu[kx] = *(const bf16x8*)(qub + (size_t)r0 * 64 + kx * 32 + rg * 8);
      aqv[kx] = *(const bf16x8*)(qvb + (size_t)r0 * 64 + kx * 32 + rg * 8);
      aqs[kx] = *(const bf16x8*)(qvb + (size_t)rs * 64 + kx * 32 + rg * 8);
    }
  }

  f32x4 zz = {0.f, 0.f, 0.f, 0.f};
  f32x4 o[4];
  float mrow[4], lrow[4];
#pragma unroll
  for (int e = 0; e < 4; ++e) { o[e] = zz; mrow[e] = -3.0e38f; lrow[e] = 0.f; }

  float* Uw = &Ulds[wid][0];
  u16* Pw = &Plds[wid][0];

  for (int jt = 0; jt < 32; ++jt) {
    const int j0 = jt * 64;
    f32x4 s[4];
#pragma unroll
    for (int ni = 0; ni < 4; ++ni) s[ni] = zz;
    // content scores: S = qu @ k^T  (16x64)
#pragma unroll
    for (int ni = 0; ni < 4; ++ni) {
      const u16* kp = kb + (size_t)(j0 + ni * 16 + colL) * 64 + rg * 8;
      bf16x8 b0 = *(const bf16x8*)kp;
      bf16x8 b1 = *(const bf16x8*)(kp + 32);
      s[ni] = MFMA16(aqu[0], b0, s[ni]);
      s[ni] = MFMA16(aqu[1], b1, s[ni]);
    }
    const int pbase = j0 + 1008 - i0;  // min p in tile = j0 + 1023 - (i0+15)
    const bool mainv = (pbase <= 2047);
    const bool leak = (pbase + 78 >= 2049);
    if (mainv) {
      // U[row][idx] = qv[i0+row] . r[pbase+idx], idx in [0,80)
#pragma unroll
      for (int uc = 0; uc < 5; ++uc) {
        int pr = pbase + uc * 16 + colL;
        pr = pr < 2047 ? pr : 2047;  // clamp; out-of-range values discarded at gather
        const u16* rp = rb + (size_t)pr * 64 + rg * 8;
        f32x4 ua = zz;
        ua = MFMA16(aqv[0], *(const bf16x8*)rp, ua);
        ua = MFMA16(aqv[1], *(const bf16x8*)(rp + 32), ua);
#pragma unroll
        for (int e = 0; e < 4; ++e) Uw[(rg * 4 + e) * 84 + uc * 16 + colL] = ua[e];
      }
      asm volatile("s_waitcnt lgkmcnt(0)" ::: "memory");
#pragma unroll
      for (int c = 0; c < 4; ++c)
#pragma unroll
        for (int e = 0; e < 4; ++e) {
          int row = rg * 4 + e;
          int idx = c * 16 + colL - row + 15;  // = p - pbase, in [0,78]
          int p = pbase + idx;
          float uval = Uw[row * 84 + idx];
          s[c][e] += (p <= 2047) ? uval : 0.f;
        }
    }
    if (leak) {
      asm volatile("s_waitcnt lgkmcnt(0)" ::: "memory");
      const int pb2 = pbase - 2049;
#pragma unroll
      for (int uc = 0; uc < 5; ++uc) {
        int pr = pb2 + uc * 16 + colL;
        pr = pr < 0 ? 0 : (pr > 2047 ? 2047 : pr);
        const u16* rp = rb + (size_t)pr * 64 + rg * 8;
        f32x4 ua = zz;
        ua = MFMA16(aqs[0], *(const bf16x8*)rp, ua);
        ua = MFMA16(aqs[1], *(const bf16x8*)(rp + 32), ua);
#pragma unroll
        for (int e = 0; e < 4; ++e) Uw[(rg * 4 + e) * 84 + uc * 16 + colL] = ua[e];
      }
      asm volatile("s_waitcnt lgkmcnt(0)" ::: "memory");
#pragma unroll
      for (int c = 0; c < 4; ++c)
#pragma unroll
        for (int e = 0; e < 4; ++e) {
          int row = rg * 4 + e;
          int idx = c * 16 + colL - row + 15;
          int p = pbase + idx;
          if (p >= 2049) s[c][e] += Uw[row * 84 + idx];
        }
    }
    // online softmax (exp2 domain; scale already folded into qu/qv)
    float tm[4];
#pragma unroll
    for (int e = 0; e < 4; ++e)
      tm[e] = fmaxf(fmaxf(s[0][e], s[1][e]), fmaxf(s[2][e], s[3][e]));
#pragma unroll
    for (int off = 8; off >= 1; off >>= 1)
#pragma unroll
      for (int e = 0; e < 4; ++e) tm[e] = fmaxf(tm[e], __shfl_xor(tm[e], off, 64));
    float fac[4];
#pragma unroll
    for (int e = 0; e < 4; ++e) {
      float mn = fmaxf(mrow[e], tm[e]);
      fac[e] = __builtin_amdgcn_exp2f(mrow[e] - mn);
      mrow[e] = mn;
    }
    float ps[4];
#pragma unroll
    for (int e = 0; e < 4; ++e) {
#pragma unroll
      for (int c = 0; c < 4; ++c) s[c][e] = __builtin_amdgcn_exp2f(s[c][e] - mrow[e]);
      ps[e] = (s[0][e] + s[1][e]) + (s[2][e] + s[3][e]);
    }
#pragma unroll
    for (int off = 8; off >= 1; off >>= 1)
#pragma unroll
      for (int e = 0; e < 4; ++e) ps[e] += __shfl_xor(ps[e], off, 64);
#pragma unroll
    for (int e = 0; e < 4; ++e) {
      lrow[e] = lrow[e] * fac[e] + ps[e];
      o[0][e] *= fac[e]; o[1][e] *= fac[e]; o[2][e] *= fac[e]; o[3][e] *= fac[e];
    }
    // P: C-layout -> LDS (bf16, 16B-chunk XOR swizzle) -> A-layout frags
#pragma unroll
    for (int c = 0; c < 4; ++c)
#pragma unroll
      for (int e = 0; e < 4; ++e) {
        int row = rg * 4 + e;
        int col = c * 16 + colL;
        int sw = (col >> 3) ^ (row & 7);
        Pw[row * 64 + sw * 8 + (col & 7)] = f2bf(s[c][e]);
      }
    asm volatile("s_waitcnt lgkmcnt(0)" ::: "memory");
    bf16x8 pa[2];
#pragma unroll
    for (int kx = 0; kx < 2; ++kx) {
      int chunk = kx * 4 + rg;
      int sw = chunk ^ (colL & 7);
      pa[kx] = *(const bf16x8*)(Pw + colL * 64 + sw * 8);
    }
    // O += P @ V  (V stored transposed: vb[d][j], contiguous along j = K dim)
#pragma unroll
    for (int ni = 0; ni < 4; ++ni) {
      const u16* vp = vb + (size_t)(ni * 16 + colL) * 2048 + j0 + rg * 8;
      bf16x8 b0 = *(const bf16x8*)vp;
      bf16x8 b1 = *(const bf16x8*)(vp + 32);
      o[ni] = MFMA16(pa[0], b0, o[ni]);
      o[ni] = MFMA16(pa[1], b1, o[ni]);
    }
    asm volatile("" ::: "memory");  // keep LDS WAR ordering across iterations
  }
  float inv[4];
#pragma unroll
  for (int e = 0; e < 4; ++e) inv[e] = 1.0f / lrow[e];
#pragma unroll
  for (int c = 0; c < 4; ++c)
#pragma unroll
    for (int e = 0; e < 4; ++e) {
      int row = rg * 4 + e;
      size_t addr = ((size_t)(b * 1024 + i0 + row)) * 1024 + h * 64 + c * 16 + colL;
      aout[addr] = f2bf(o[c][e] * inv[e]);
    }
}

// ---------------- output projection ----------------
__global__ __launch_bounds__(256, 2) void gemm_out(
    const u16* __restrict__ aob, const u16* __restrict__ wob, float* __restrict__ out) {
  __shared__ u16 As[128 * 32], Bs[128 * 32];
  const int bid = blockIdx.x;
  const int mt = bid >> 3, nt = bid & 7;
  const int m0 = mt * 128, n0 = nt * 128;
  f32x4 acc[4][4];
  f32x4 zz = {0.f, 0.f, 0.f, 0.f};
#pragma unroll
  for (int a1 = 0; a1 < 4; ++a1)
#pragma unroll
    for (int a2 = 0; a2 < 4; ++a2) acc[a1][a2] = zz;
  gemm_core(aob, wob, As, Bs, m0, n0, false, acc);
  const int t = threadIdx.x, lane = t & 63, wid = t >> 6;
  const int colL = lane & 15, rg = lane >> 4;
  const int wm = (wid >> 1) * 64, wn = (wid & 1) * 64;
#pragma unroll
  for (int mi = 0; mi < 4; ++mi)
#pragma unroll
    for (int ni = 0; ni < 4; ++ni)
#pragma unroll
      for (int e = 0; e < 4; ++e) {
        int m = m0 + wm + mi * 16 + rg * 4 + e;
        int n = n0 + wn + ni * 16 + colL;
        out[(size_t)m * 1024 + n] = acc[mi][ni][e];
      }
}

// ---------------- host ----------------
extern "C" void kernel_launch(void* const* d_in, const int* in_sizes, int n_in,
                              void* d_out, int out_size, void* d_ws, size_t ws_size,
                              hipStream_t stream) {
  (void)in_sizes; (void)n_in; (void)out_size; (void)ws_size;
  const float* x = (const float*)d_in[0];
  const float* mem = (const float*)d_in[1];
  const float* pos = (const float*)d_in[2];
  const float* qw = (const float*)d_in[3];
  const float* kw = (const float*)d_in[4];
  const float* vw = (const float*)d_in[5];
  const float* rw = (const float*)d_in[6];
  const float* ow = (const float*)d_in[7];
  const float* bu = (const float*)d_in[8];
  const float* bv = (const float*)d_in[9];
  float* out = (float*)d_out;

  char* w = (char*)d_ws;
  u16* catb = (u16*)(w + 0);          //  8 MB  [2][2048][1024]
  u16* posb = (u16*)(w + 8388608);    //  4 MB  [2048][1024]
  u16* wqb  = (u16*)(w + 12582912);   //  2 MB
  u16* wkb  = (u16*)(w + 14680064);   //  2 MB
  u16* wvb  = (u16*)(w + 16777216);   //  2 MB
  u16* wrb  = (u16*)(w + 18874368);   //  2 MB
  u16* wob  = (u16*)(w + 20971520);   //  2 MB
  u16* qub  = (u16*)(w + 23068672);   //  4 MB  [B*H][1024][64], bias_u + scale folded
  u16* qvb  = (u16*)(w + 27262976);   //  4 MB  [B*H][1024][64], bias_v + scale folded
  u16* kbuf = (u16*)(w + 31457280);   //  8 MB  [B*H][2048][64]
  u16* vtb  = (u16*)(w + 39845888);   //  8 MB  [B*H][64][2048] (transposed)
  u16* rbuf = (u16*)(w + 48234496);   //  4 MB  [H][2048][64]
  u16* aob  = (u16*)(w + 52428800);   //  4 MB  [B*T][1024]

  prep_kernel<<<dim3(4096, 7), 256, 0, stream>>>(x, mem, pos, qw, kw, vw, rw, ow,
                                                 catb, posb, wqb, wkb, wvb, wrb, wob);
  gemm_qr<<<256, 256, 0, stream>>>(catb, posb, wqb, wrb, bu, bv, qub, qvb, rbuf);
  gemm_kv<<<512, 256, 0, stream>>>(catb, wkb, wvb, kbuf, vtb);
  attn_kernel<<<512, 256, 0, stream>>>(qub, qvb, kbuf, vtb, rbuf, aob);
  gemm_out<<<128, 256, 0, stream>>>(aob, wob, out);
}